// Round 1
// baseline (709.769 us; speedup 1.0000x reference)
//
#include <hip/hip_runtime.h>

#define Bsz 8
#define Tsz 16384
#define Dsz 256
#define Hsz 256
#define Osz 256
#define TP1 16385  // T+1 scan length

typedef __attribute__((ext_vector_type(4))) float f32x4;
typedef __attribute__((ext_vector_type(8))) short bf16x8;
typedef __attribute__((ext_vector_type(4))) short bf16x4;

__device__ inline short f2bf(float f) {
  // round-to-nearest-even fp32 -> bf16 (values here are tame; no NaN handling)
  unsigned u = __builtin_bit_cast(unsigned, f);
  u += 0x7FFFu + ((u >> 16) & 1u);
  return (short)(u >> 16);
}

// ---------------------------------------------------------------- sentinel
__global__ void fill_sentinel(float* __restrict__ out, int n) {
  int i = blockIdx.x * blockDim.x + threadIdx.x;
  if (i < n) out[i] = 12345.0f;
}

// ---------------------------------------------------------------- init e0 = (1,0)
__global__ void init_e0(float* __restrict__ a, float* __restrict__ b) {
  int idx = blockIdx.x * blockDim.x + threadIdx.x;
  if (idx >= Bsz * Hsz) return;
  int batch = idx >> 8, h = idx & 255;
  size_t off = (size_t)batch * TP1 * Hsz + h;
  a[off] = 1.0f;
  b[off] = 0.0f;
}

// ---------------------------------------------------------------- GEMM 1: z,h -> level-0 (a,b)
// block: 256 thr (4 waves, 2x2), tile M=128 rows x N=64 h-cols, K=256 full.
// Each block computes BOTH z and h for its h-cols (needed fused for b = z*h).
__global__ __launch_bounds__(256, 2)
void gemm_zh(const float* __restrict__ xs,
             const float* __restrict__ Wz, const float* __restrict__ bz,
             const float* __restrict__ Wh, const float* __restrict__ bh,
             float* __restrict__ l0a, float* __restrict__ l0b)
{
  __shared__ __align__(16) short lz[64][264];  // +8 shorts pad: 2-way bank alias only (free)
  __shared__ __align__(16) short lh[64][264];

  const int bid   = blockIdx.x;
  const int nTile = bid & 3;        // N-tile fastest -> consecutive blocks share xs rows (L2)
  const int mTile = bid >> 2;
  const int rowBase = mTile * 128;
  const int hBase   = nTile * 64;
  const int tid = threadIdx.x;

  // stage weight tiles fp32 -> bf16 into LDS (once per block)
  for (int it = tid; it < 64 * 64; it += 256) {
    const int r  = it >> 6;
    const int c4 = (it & 63) << 2;
    const size_t go = (size_t)(hBase + r) * Dsz + c4;
    f32x4 vz = *(const f32x4*)(Wz + go);
    f32x4 vh = *(const f32x4*)(Wh + go);
    bf16x4 sz, sh;
#pragma unroll
    for (int j = 0; j < 4; ++j) { sz[j] = f2bf(vz[j]); sh[j] = f2bf(vh[j]); }
    *(bf16x4*)&lz[r][c4] = sz;
    *(bf16x4*)&lh[r][c4] = sh;
  }
  __syncthreads();

  const int wave = tid >> 6, lane = tid & 63;
  const int wm = (wave >> 1) * 64;   // wave row offset
  const int wn = (wave & 1) * 32;    // wave h-col offset
  const int l15 = lane & 15, l4 = lane >> 4;

  f32x4 accz[4][2] = {};
  f32x4 acch[4][2] = {};

  const float* aRow = xs + (size_t)(rowBase + wm + l15) * Dsz + l4 * 8;

#pragma unroll
  for (int kk = 0; kk < 8; ++kk) {
    bf16x8 af[4];
#pragma unroll
    for (int m = 0; m < 4; ++m) {
      const float* p = aRow + (size_t)m * 16 * Dsz + kk * 32;
      f32x4 f0 = *(const f32x4*)p;
      f32x4 f1 = *(const f32x4*)(p + 4);
      bf16x8 v;
      v[0] = f2bf(f0[0]); v[1] = f2bf(f0[1]); v[2] = f2bf(f0[2]); v[3] = f2bf(f0[3]);
      v[4] = f2bf(f1[0]); v[5] = f2bf(f1[1]); v[6] = f2bf(f1[2]); v[7] = f2bf(f1[3]);
      af[m] = v;
    }
    bf16x8 bzf[2], bhf[2];
#pragma unroll
    for (int n = 0; n < 2; ++n) {
      bzf[n] = *(const bf16x8*)&lz[wn + n * 16 + l15][kk * 32 + l4 * 8];
      bhf[n] = *(const bf16x8*)&lh[wn + n * 16 + l15][kk * 32 + l4 * 8];
    }
#pragma unroll
    for (int m = 0; m < 4; ++m)
#pragma unroll
      for (int n = 0; n < 2; ++n) {
        accz[m][n] = __builtin_amdgcn_mfma_f32_16x16x32_bf16(af[m], bzf[n], accz[m][n], 0, 0, 0);
        acch[m][n] = __builtin_amdgcn_mfma_f32_16x16x32_bf16(af[m], bhf[n], acch[m][n], 0, 0, 0);
      }
  }

  // epilogue: z = sigmoid(.+bz), h = .+bh ; a = 1-z, b = z*h at L0 index t+1
#pragma unroll
  for (int n = 0; n < 2; ++n) {
    const int col = hBase + wn + n * 16 + l15;
    const float bzv = bz[col], bhv = bh[col];
#pragma unroll
    for (int m = 0; m < 4; ++m) {
#pragma unroll
      for (int j = 0; j < 4; ++j) {
        const int row = rowBase + wm + m * 16 + l4 * 4 + j;
        const int batch = row >> 14, t = row & (Tsz - 1);
        const size_t off = ((size_t)batch * TP1 + t + 1) * Hsz + col;
        const float zv = 1.0f / (1.0f + expf(-(accz[m][n][j] + bzv)));
        const float hv = acch[m][n][j] + bhv;
        l0a[off] = 1.0f - zv;
        l0b[off] = zv * hv;
      }
    }
  }
}

// ---------------------------------------------------------------- up-sweep: red[i] = c(e[2i], e[2i+1])
// c((a0,b0),(a1,b1)) = (a0*b0, b0*a1 + b1)   -- NON-associative, matches JAX tree
__global__ void upsweep(const float* __restrict__ sA, const float* __restrict__ sB,
                        float* __restrict__ dA, float* __restrict__ dB,
                        int nSrc, int nDst)
{
  int idx = blockIdx.x * blockDim.x + threadIdx.x;
  int total = Bsz * nDst * (Hsz / 4);
  if (idx >= total) return;
  int h4 = idx & 63;
  int r = idx >> 6;
  int i = r % nDst;
  int batch = r / nDst;
  size_t s = ((size_t)batch * nSrc + 2 * i) * Hsz + h4 * 4;
  f32x4 a0 = *(const f32x4*)(sA + s);
  f32x4 b0 = *(const f32x4*)(sB + s);
  f32x4 a1 = *(const f32x4*)(sA + s + Hsz);
  f32x4 b1 = *(const f32x4*)(sB + s + Hsz);
  size_t d = ((size_t)batch * nDst + i) * Hsz + h4 * 4;
  *(f32x4*)(dA + d) = a0 * b0;
  *(f32x4*)(dB + d) = b0 * a1 + b1;
}

// ---------------------------------------------------------------- down-sweep (b only, in place)
// res[2i+1] = odd_b[i];  res[2i+2] = odd_b[i]*eA[2i+2] + eB[2i+2];  res[0] = eB[0] (untouched)
__global__ void downsweep(const float* __restrict__ scanNext,  // [B][nK1][H] = scan of level k+1
                          const float* __restrict__ eA, float* __restrict__ eB,  // level k
                          int nK, int nK1)
{
  int idx = blockIdx.x * blockDim.x + threadIdx.x;
  int total = Bsz * nK1 * (Hsz / 4);
  if (idx >= total) return;
  int h4 = idx & 63;
  int r = idx >> 6;
  int i = r % nK1;
  int batch = r / nK1;
  f32x4 ob = *(const f32x4*)(scanNext + ((size_t)batch * nK1 + i) * Hsz + h4 * 4);
  size_t o1 = ((size_t)batch * nK + 2 * i + 1) * Hsz + h4 * 4;
  *(f32x4*)(eB + o1) = ob;
  if (2 * i + 2 < nK) {
    f32x4 a2 = *(const f32x4*)(eA + o1 + Hsz);
    f32x4 b2 = *(const f32x4*)(eB + o1 + Hsz);
    *(f32x4*)(eB + o1 + Hsz) = ob * a2 + b2;
  }
}

// ---------------------------------------------------------------- GEMM 2: out = states[:,1:] @ Wo^T + bo
// block: 256 thr (4 waves, 2x2), tile M=128 x N=128, K=256.
__global__ __launch_bounds__(256, 2)
void gemm_out(const float* __restrict__ scanB, const float* __restrict__ Wo,
              const float* __restrict__ bo, float* __restrict__ out)
{
  __shared__ __align__(16) short lw[128][264];

  const int bid   = blockIdx.x;
  const int nTile = bid & 1;
  const int mTile = bid >> 1;
  const int rowBase = mTile * 128;
  const int oBase   = nTile * 128;
  const int tid = threadIdx.x;

  for (int it = tid; it < 128 * 64; it += 256) {
    const int r  = it >> 6;
    const int c4 = (it & 63) << 2;
    f32x4 v = *(const f32x4*)(Wo + (size_t)(oBase + r) * Hsz + c4);
    bf16x4 s;
#pragma unroll
    for (int j = 0; j < 4; ++j) s[j] = f2bf(v[j]);
    *(bf16x4*)&lw[r][c4] = s;
  }
  __syncthreads();

  const int wave = tid >> 6, lane = tid & 63;
  const int wm = (wave >> 1) * 64, wn = (wave & 1) * 64;
  const int l15 = lane & 15, l4 = lane >> 4;

  f32x4 acc[4][4] = {};

#pragma unroll
  for (int kk = 0; kk < 8; ++kk) {
    bf16x8 af[4];
#pragma unroll
    for (int m = 0; m < 4; ++m) {
      const int row = rowBase + wm + m * 16 + l15;
      const int batch = row >> 14, t = row & (Tsz - 1);
      const float* p = scanB + ((size_t)batch * TP1 + t + 1) * Hsz + kk * 32 + l4 * 8;
      f32x4 f0 = *(const f32x4*)p;
      f32x4 f1 = *(const f32x4*)(p + 4);
      bf16x8 v;
      v[0] = f2bf(f0[0]); v[1] = f2bf(f0[1]); v[2] = f2bf(f0[2]); v[3] = f2bf(f0[3]);
      v[4] = f2bf(f1[0]); v[5] = f2bf(f1[1]); v[6] = f2bf(f1[2]); v[7] = f2bf(f1[3]);
      af[m] = v;
    }
    bf16x8 bf_[4];
#pragma unroll
    for (int n = 0; n < 4; ++n)
      bf_[n] = *(const bf16x8*)&lw[wn + n * 16 + l15][kk * 32 + l4 * 8];
#pragma unroll
    for (int m = 0; m < 4; ++m)
#pragma unroll
      for (int n = 0; n < 4; ++n)
        acc[m][n] = __builtin_amdgcn_mfma_f32_16x16x32_bf16(af[m], bf_[n], acc[m][n], 0, 0, 0);
  }

#pragma unroll
  for (int n = 0; n < 4; ++n) {
    const int col = oBase + wn + n * 16 + l15;
    const float bv = bo[col];
#pragma unroll
    for (int m = 0; m < 4; ++m)
#pragma unroll
      for (int j = 0; j < 4; ++j) {
        const int row = rowBase + wm + m * 16 + l4 * 4 + j;
        out[(size_t)row * Osz + col] = acc[m][n][j] + bv;
      }
  }
}

// ================================================================ host
extern "C" void kernel_launch(void* const* d_in, const int* in_sizes, int n_in,
                              void* d_out, int out_size, void* d_ws, size_t ws_size,
                              hipStream_t stream)
{
  (void)in_sizes; (void)n_in;
  const float* xs = (const float*)d_in[0];
  const float* Wz = (const float*)d_in[1];
  const float* bz = (const float*)d_in[2];
  const float* Wh = (const float*)d_in[3];
  const float* bh = (const float*)d_in[4];
  const float* Wo = (const float*)d_in[5];
  const float* bo = (const float*)d_in[6];
  float* out = (float*)d_out;

  // level sizes of JAX's odd-even recursion on 16385 elements
  static const int nlv[15] = {16385, 8192, 4096, 2048, 1024, 512, 256, 128, 64, 32, 16, 8, 4, 2, 1};
  size_t cum[16];
  cum[0] = 0;
  for (int k = 0; k < 15; ++k) cum[k + 1] = cum[k] + (size_t)nlv[k];
  const size_t compFloats = (size_t)Bsz * Hsz * cum[15];          // per component (a or b)
  const size_t need = compFloats * 2 * sizeof(float);             // = 512 MiB exactly
  if (ws_size < need) {
    // diagnosable failure: output becomes 12345.0 everywhere
    fill_sentinel<<<(out_size + 255) / 256, 256, 0, stream>>>(out, out_size);
    return;
  }

  float* compA = (float*)d_ws;
  float* compB = compA + compFloats;
  float* LA[15];
  float* LB[15];
  for (int k = 0; k < 15; ++k) {
    LA[k] = compA + (size_t)Bsz * Hsz * cum[k];
    LB[k] = compB + (size_t)Bsz * Hsz * cum[k];
  }

  // 1) level-0: e0 = (1,0); e[t+1] = (1-z_t, z_t*h_t)
  init_e0<<<(Bsz * Hsz + 255) / 256, 256, 0, stream>>>(LA[0], LB[0]);
  gemm_zh<<<(Bsz * Tsz / 128) * 4, 256, 0, stream>>>(xs, Wz, bz, Wh, bh, LA[0], LB[0]);

  // 2) up-sweep (pairwise reductions, 14 levels)
  for (int k = 0; k < 14; ++k) {
    int total = Bsz * nlv[k + 1] * (Hsz / 4);
    upsweep<<<(total + 255) / 256, 256, 0, stream>>>(LA[k], LB[k], LA[k + 1], LB[k + 1],
                                                     nlv[k], nlv[k + 1]);
  }

  // 3) down-sweep (b-only, in place; scan at L14 == elems, nothing to do there)
  for (int k = 13; k >= 0; --k) {
    int total = Bsz * nlv[k + 1] * (Hsz / 4);
    downsweep<<<(total + 255) / 256, 256, 0, stream>>>(LB[k + 1], LA[k], LB[k],
                                                       nlv[k], nlv[k + 1]);
  }

  // 4) output projection from scan b (states[:,1:]) — reads L0 index t+1
  gemm_out<<<(Bsz * Tsz / 128) * 2, 256, 0, stream>>>(LB[0], Wo, bo, out);
}

// Round 3
// 318.306 us; speedup vs baseline: 2.2298x; 2.2298x over previous
//
#include <hip/hip_runtime.h>

#define Bsz 8
#define Tsz 16384
#define Hsz 256
#define NL0 16385
#define NL5 512
#define NL10 16

typedef __attribute__((ext_vector_type(2))) float f32x2;
typedef __attribute__((ext_vector_type(4))) float f32x4;
typedef __attribute__((ext_vector_type(8))) short bf16x8;

__device__ __forceinline__ short f2bf(float f) {
  unsigned u = __builtin_bit_cast(unsigned, f);
  u += 0x7FFFu + ((u >> 16) & 1u);
  return (short)(u >> 16);
}
__device__ __forceinline__ bf16x8 pack8(f32x4 a, f32x4 b) {
  bf16x8 v;
  v[0] = f2bf(a[0]); v[1] = f2bf(a[1]); v[2] = f2bf(a[2]); v[3] = f2bf(a[3]);
  v[4] = f2bf(b[0]); v[5] = f2bf(b[1]); v[6] = f2bf(b[2]); v[7] = f2bf(b[3]);
  return v;
}

// ---------------------------------------------------------------- sentinel
__global__ void fill_sentinel(float* __restrict__ out, int n) {
  int i = blockIdx.x * blockDim.x + threadIdx.x;
  if (i < n) out[i] = 12345.0f;
}

// ---------------------------------------------------------------- weight prep: fp32 [256][256] -> bf16 tiled [c/8][r][c%8]
__global__ void prep_weights(const float* __restrict__ Wz, const float* __restrict__ Wh,
                             const float* __restrict__ Wo, unsigned short* __restrict__ wt) {
  int idx = blockIdx.x * 256 + threadIdx.x;          // 3 * 256 * 32
  if (idx >= 3 * 256 * 32) return;
  int m   = idx >> 13;
  int rem = idx & 8191;
  int r   = rem >> 5;
  int cq  = rem & 31;
  const float* src = (m == 0 ? Wz : (m == 1 ? Wh : Wo)) + r * 256 + cq * 8;
  f32x4 v0 = *(const f32x4*)src;
  f32x4 v1 = *(const f32x4*)(src + 4);
  *(bf16x8*)(wt + m * 65536 + (cq * 256 + r) * 8) = pack8(v0, v1);
}

// ---------------------------------------------------------------- init element 0 of L0: (a,b) = (1,0)
__global__ void init_e0(f32x2* __restrict__ l0ab) {
  int idx = blockIdx.x * 256 + threadIdx.x;
  if (idx >= Bsz * 256) return;
  int batch = idx >> 8, h = idx & 255;
  l0ab[(size_t)batch * NL0 * 256 + h] = f32x2{1.0f, 0.0f};
}

// ---------------------------------------------------------------- GEMM 1: full-H tile, M=64, z & h fused
// LDS: A [4][64][8] bf16 + Wz [4][256][8] + Wh [4][256][8] = 36 KB. K-step 32, 8 steps.
__global__ __launch_bounds__(256, 2)
void gemm_zh(const float* __restrict__ xs, const unsigned short* __restrict__ wt,
             const float* __restrict__ bz, const float* __restrict__ bh,
             f32x2* __restrict__ l0ab)
{
  extern __shared__ char smem[];
  unsigned short* aL = (unsigned short*)smem;   // 2048 shorts
  unsigned short* zL = aL + 2048;               // 8192 shorts
  unsigned short* hL = zL + 8192;               // 8192 shorts

  const int tid = threadIdx.x;
  const int wave = tid >> 6, lane = tid & 63, l15 = lane & 15, l4 = lane >> 4;
  const int rowBase = blockIdx.x * 64;
  const unsigned short* wz_t = wt;
  const unsigned short* wh_t = wt + 65536;

  f32x4 accz[4][4] = {};
  f32x4 acch[4][4] = {};

  const int arow = tid >> 2, akq = tid & 3;     // A stage: row, k-quad (8 k each)
  const float* aptr = xs + (size_t)(rowBase + arow) * 256 + akq * 8;

  f32x4 areg0 = *(const f32x4*)(aptr);
  f32x4 areg1 = *(const f32x4*)(aptr + 4);

  for (int s = 0; s < 8; ++s) {
    // stage A (converted) and W (bf16 linear copy: 32 shorts = 4x bf16x8 per thread per matrix)
    *(bf16x8*)(aL + (akq * 64 + arow) * 8) = pack8(areg0, areg1);
    {
      const unsigned short* gz = wz_t + s * 8192 + tid * 32;
      const unsigned short* gh = wh_t + s * 8192 + tid * 32;
      bf16x8 z0 = *(const bf16x8*)(gz);
      bf16x8 z1 = *(const bf16x8*)(gz + 8);
      bf16x8 z2 = *(const bf16x8*)(gz + 16);
      bf16x8 z3 = *(const bf16x8*)(gz + 24);
      bf16x8 h0 = *(const bf16x8*)(gh);
      bf16x8 h1 = *(const bf16x8*)(gh + 8);
      bf16x8 h2 = *(const bf16x8*)(gh + 16);
      bf16x8 h3 = *(const bf16x8*)(gh + 24);
      unsigned short* lz = zL + tid * 32;
      unsigned short* lh = hL + tid * 32;
      *(bf16x8*)(lz)      = z0;  *(bf16x8*)(lz + 8)  = z1;
      *(bf16x8*)(lz + 16) = z2;  *(bf16x8*)(lz + 24) = z3;
      *(bf16x8*)(lh)      = h0;  *(bf16x8*)(lh + 8)  = h1;
      *(bf16x8*)(lh + 16) = h2;  *(bf16x8*)(lh + 24) = h3;
    }
    __syncthreads();
    // prefetch next A (overlaps MFMA)
    if (s < 7) {
      areg0 = *(const f32x4*)(aptr + (s + 1) * 32);
      areg1 = *(const f32x4*)(aptr + (s + 1) * 32 + 4);
    }
    const int wn = wave * 64;
    bf16x8 af[4], zf[4], hf[4];
#pragma unroll
    for (int m = 0; m < 4; ++m)
      af[m] = *(const bf16x8*)(aL + (l4 * 64 + m * 16 + l15) * 8);
#pragma unroll
    for (int n = 0; n < 4; ++n) {
      zf[n] = *(const bf16x8*)(zL + (l4 * 256 + wn + n * 16 + l15) * 8);
      hf[n] = *(const bf16x8*)(hL + (l4 * 256 + wn + n * 16 + l15) * 8);
    }
#pragma unroll
    for (int m = 0; m < 4; ++m)
#pragma unroll
      for (int n = 0; n < 4; ++n) {
        accz[m][n] = __builtin_amdgcn_mfma_f32_16x16x32_bf16(af[m], zf[n], accz[m][n], 0, 0, 0);
        acch[m][n] = __builtin_amdgcn_mfma_f32_16x16x32_bf16(af[m], hf[n], acch[m][n], 0, 0, 0);
      }
    __syncthreads();
  }

  const int wn = wave * 64;
#pragma unroll
  for (int n = 0; n < 4; ++n) {
    const int col = wn + n * 16 + l15;
    const float bzv = bz[col], bhv = bh[col];
#pragma unroll
    for (int m = 0; m < 4; ++m)
#pragma unroll
      for (int j = 0; j < 4; ++j) {
        const int row = rowBase + m * 16 + l4 * 4 + j;
        const int batch = row >> 14, t = row & (Tsz - 1);
        const size_t off = ((size_t)batch * NL0 + t + 1) * 256 + col;
        const float zv = 1.0f / (1.0f + expf(-(accz[m][n][j] + bzv)));
        const float hv = acch[m][n][j] + bhv;
        l0ab[off] = f32x2{1.0f - zv, zv * hv};
      }
  }
}

// ---------------------------------------------------------------- chunk up-sweep: 32 src elements -> 1 dst (5 levels)
__global__ __launch_bounds__(256)
void chunk_up(const f32x2* __restrict__ src, f32x2* __restrict__ dst, int nCh, int nSrc)
{
  int idx = blockIdx.x * 256 + threadIdx.x;
  int total = Bsz * nCh * 256;
  if (idx >= total) return;
  int h = idx & 255, r = idx >> 8;
  int c = r % nCh, batch = r / nCh;
  size_t base = ((size_t)batch * nSrc + (size_t)c * 32) * 256 + h;

  float a1[16], b1[16];
#pragma unroll
  for (int i = 0; i < 16; ++i) {
    f32x2 e0 = src[base + (size_t)(2 * i) * 256];
    f32x2 e1 = src[base + (size_t)(2 * i + 1) * 256];
    a1[i] = e0[0] * e0[1];
    b1[i] = e0[1] * e1[0] + e1[1];
  }
#pragma unroll
  for (int n = 8; n >= 1; n >>= 1) {
#pragma unroll
    for (int i = 0; i < n; ++i) {
      float na = a1[2 * i] * b1[2 * i];
      float nb = b1[2 * i] * a1[2 * i + 1] + b1[2 * i + 1];
      a1[i] = na; b1[i] = nb;
    }
  }
  dst[((size_t)batch * nCh + c) * 256 + h] = f32x2{a1[0], b1[0]};
}

// ---------------------------------------------------------------- 16-element full tree scan (top levels), writes exact b-scan
__global__ void tree16(const f32x2* __restrict__ src, float* __restrict__ outB)
{
  int idx = blockIdx.x * 256 + threadIdx.x;
  if (idx >= Bsz * 256) return;
  int h = idx & 255, batch = idx >> 8;
  size_t base = (size_t)batch * 16 * 256 + h;

  float a0[16], b0[16];
#pragma unroll
  for (int i = 0; i < 16; ++i) { f32x2 e = src[base + (size_t)i * 256]; a0[i] = e[0]; b0[i] = e[1]; }
  float a1[8], b1[8];
#pragma unroll
  for (int i = 0; i < 8; ++i) { a1[i] = a0[2*i]*b0[2*i]; b1[i] = b0[2*i]*a0[2*i+1] + b0[2*i+1]; }
  float a2[4], b2[4];
#pragma unroll
  for (int i = 0; i < 4; ++i) { a2[i] = a1[2*i]*b1[2*i]; b2[i] = b1[2*i]*a1[2*i+1] + b1[2*i+1]; }
  float a3[2], b3[2];
#pragma unroll
  for (int i = 0; i < 2; ++i) { a3[i] = a2[2*i]*b2[2*i]; b3[i] = b2[2*i]*a2[2*i+1] + b2[2*i+1]; }
  float s3[2];
  s3[0] = b3[0];
  s3[1] = b3[0] * a3[1] + b3[1];
  float s2[4];
  s2[0] = b2[0];
  s2[1] = s3[0];
  s2[2] = s3[0] * a2[2] + b2[2];
  s2[3] = s3[1];
  float s1[8];
  s1[0] = b1[0];
#pragma unroll
  for (int j = 0; j < 4; ++j) s1[2*j+1] = s2[j];
#pragma unroll
  for (int j = 1; j < 4; ++j) s1[2*j] = s2[j-1] * a1[2*j] + b1[2*j];
  float s0[16];
  s0[0] = b0[0];
#pragma unroll
  for (int j = 0; j < 8; ++j) s0[2*j+1] = s1[j];
#pragma unroll
  for (int j = 1; j < 8; ++j) s0[2*j] = s1[j-1] * a0[2*j] + b0[2*j];
#pragma unroll
  for (int i = 0; i < 16; ++i) outB[base + (size_t)i * 256] = s0[i];
}

// ---------------------------------------------------------------- chunk down-sweep
// Needs BOTH P = snext[c-1] (prefix, leading-even entries, all-odd chain collapses to it)
// and S = snext[c] (the chunk's own top: odd-index entries do NOT satisfy the sequential
// recurrence for this non-associative operator, so S must be the exact global value).
template <bool BF16>
__global__ __launch_bounds__(256, 2)
void chunk_down(const f32x2* __restrict__ src, const float* __restrict__ snext,
                void* __restrict__ outv, int nCh, int nFull, int nSrc)
{
  int idx = blockIdx.x * 256 + threadIdx.x;
  int total = Bsz * nCh * 256;
  if (idx >= total) return;
  int h = idx & 255, r = idx >> 8;
  int c = r % nCh, batch = r / nCh;
  size_t base = ((size_t)batch * nSrc + (size_t)c * 32) * 256 + h;
  bool hasP = (c > 0);
  float P = hasP ? snext[((size_t)batch * nFull + (c - 1)) * 256 + h] : 0.0f;
  float* outF = (float*)outv;
  unsigned short* outU = (unsigned short*)outv;

  if (c >= nFull) {                       // partial tail chunk (single element, c>0 guaranteed)
    f32x2 e = src[base];
    float v = P * e[0] + e[1];
    if (BF16) outU[base] = (unsigned short)f2bf(v); else outF[base] = v;
    return;
  }

  float S = snext[((size_t)batch * nFull + c) * 256 + h];

  float ae[16], be[16], a1[16], b1[16];
#pragma unroll
  for (int i = 0; i < 16; ++i) {
    f32x2 e0 = src[base + (size_t)(2 * i) * 256];
    f32x2 e1 = src[base + (size_t)(2 * i + 1) * 256];
    ae[i] = e0[0]; be[i] = e0[1];
    a1[i] = e0[0] * e0[1];
    b1[i] = e0[1] * e1[0] + e1[1];
  }
  float a2[8], b2[8];
#pragma unroll
  for (int i = 0; i < 8; ++i) { a2[i] = a1[2*i]*b1[2*i]; b2[i] = b1[2*i]*a1[2*i+1] + b1[2*i+1]; }
  float a3[4], b3[4];
#pragma unroll
  for (int i = 0; i < 4; ++i) { a3[i] = a2[2*i]*b2[2*i]; b3[i] = b2[2*i]*a2[2*i+1] + b2[2*i+1]; }
  float a4[2], b4[2];
#pragma unroll
  for (int i = 0; i < 2; ++i) { a4[i] = a3[2*i]*b3[2*i]; b4[i] = b3[2*i]*a3[2*i+1] + b3[2*i+1]; }

  float s5 = S;                           // exact global next-level scan value
  float s4[2];
  s4[0] = hasP ? P * a4[0] + b4[0] : b4[0];
  s4[1] = s5;
  float s3[4];
  s3[0] = hasP ? P * a3[0] + b3[0] : b3[0];
  s3[1] = s4[0];
  s3[2] = s4[0] * a3[2] + b3[2];
  s3[3] = s4[1];
  float s2[8];
  s2[0] = hasP ? P * a2[0] + b2[0] : b2[0];
#pragma unroll
  for (int j = 0; j < 4; ++j) s2[2*j+1] = s3[j];
#pragma unroll
  for (int j = 1; j < 4; ++j) s2[2*j] = s3[j-1] * a2[2*j] + b2[2*j];
  float s1[16];
  s1[0] = hasP ? P * a1[0] + b1[0] : b1[0];
#pragma unroll
  for (int j = 0; j < 8; ++j) s1[2*j+1] = s2[j];
#pragma unroll
  for (int j = 1; j < 8; ++j) s1[2*j] = s2[j-1] * a1[2*j] + b1[2*j];

  // emit src-level scan_b (32 values)
  {
    float v = hasP ? P * ae[0] + be[0] : be[0];
    if (BF16) outU[base] = (unsigned short)f2bf(v); else outF[base] = v;
  }
#pragma unroll
  for (int j = 0; j < 16; ++j) {
    float v = s1[j];
    size_t o = base + (size_t)(2 * j + 1) * 256;
    if (BF16) outU[o] = (unsigned short)f2bf(v); else outF[o] = v;
  }
#pragma unroll
  for (int j = 1; j < 16; ++j) {
    float v = s1[j-1] * ae[j] + be[j];
    size_t o = base + (size_t)(2 * j) * 256;
    if (BF16) outU[o] = (unsigned short)f2bf(v); else outF[o] = v;
  }
}

// ---------------------------------------------------------------- GEMM 2: out = scan_b[:,1:] @ Wo^T + bo, bf16 inputs
// tile 128x128, LDS Wo [16 ks][128 col][8] per phase (2 phases)
__global__ __launch_bounds__(256, 2)
void gemm_out(const unsigned short* __restrict__ s0b, const unsigned short* __restrict__ wo_t,
              const float* __restrict__ bo, float* __restrict__ out)
{
  extern __shared__ char smem[];
  unsigned short* wL = (unsigned short*)smem;   // [16][128][8] = 16384 shorts = 32 KB

  const int tid = threadIdx.x, wave = tid >> 6, lane = tid & 63, l15 = lane & 15, l4 = lane >> 4;
  const int oBase = (blockIdx.x & 1) * 128;
  const int rowBase = (blockIdx.x >> 1) * 128;
  const int wm = (wave >> 1) * 64, wn = (wave & 1) * 64;

  f32x4 acc[4][4] = {};

  for (int p = 0; p < 2; ++p) {
    // stage 16 k-slices: per thread 64 shorts (8x bf16x8), 16 threads per k-slice
    {
      const int ksl = tid >> 4, sub = tid & 15;
      const unsigned short* g = wo_t + (p * 16 + ksl) * 2048 + oBase * 8 + sub * 64;
      unsigned short* l = wL + ksl * 1024 + sub * 64;
#pragma unroll
      for (int q = 0; q < 8; ++q) {
        bf16x8 v = *(const bf16x8*)(g + q * 8);
        *(bf16x8*)(l + q * 8) = v;
      }
    }
    __syncthreads();
#pragma unroll
    for (int kk = 0; kk < 4; ++kk) {
      const int kkg = p * 4 + kk;
      bf16x8 af[4], wf[4];
#pragma unroll
      for (int m = 0; m < 4; ++m) {
        const int row = rowBase + wm + m * 16 + l15;
        const int batch = row >> 14, t = row & (Tsz - 1);
        af[m] = *(const bf16x8*)(s0b + ((size_t)batch * NL0 + t + 1) * 256 + kkg * 32 + l4 * 8);
      }
#pragma unroll
      for (int n = 0; n < 4; ++n)
        wf[n] = *(const bf16x8*)(wL + ((kk * 4 + l4) * 128 + wn + n * 16 + l15) * 8);
#pragma unroll
      for (int m = 0; m < 4; ++m)
#pragma unroll
        for (int n = 0; n < 4; ++n)
          acc[m][n] = __builtin_amdgcn_mfma_f32_16x16x32_bf16(af[m], wf[n], acc[m][n], 0, 0, 0);
    }
    __syncthreads();
  }

#pragma unroll
  for (int n = 0; n < 4; ++n) {
    const int col = oBase + wn + n * 16 + l15;
    const float bv = bo[col];
#pragma unroll
    for (int m = 0; m < 4; ++m)
#pragma unroll
      for (int j = 0; j < 4; ++j) {
        const int row = rowBase + wm + m * 16 + l4 * 4 + j;
        out[(size_t)row * 256 + col] = acc[m][n][j] + bv;
      }
  }
}

// ================================================================ host
extern "C" void kernel_launch(void* const* d_in, const int* in_sizes, int n_in,
                              void* d_out, int out_size, void* d_ws, size_t ws_size,
                              hipStream_t stream)
{
  (void)in_sizes; (void)n_in;
  const float* xs = (const float*)d_in[0];
  const float* Wz = (const float*)d_in[1];
  const float* bz = (const float*)d_in[2];
  const float* Wh = (const float*)d_in[3];
  const float* bh = (const float*)d_in[4];
  const float* Wo = (const float*)d_in[5];
  const float* bo = (const float*)d_in[6];
  float* out = (float*)d_out;

  const size_t n_l0  = (size_t)Bsz * NL0 * 256;
  const size_t n_l5  = (size_t)Bsz * NL5 * 256;
  const size_t n_l10 = (size_t)Bsz * NL10 * 256;

  f32x2* l0ab  = (f32x2*)d_ws;
  f32x2* l5ab  = l0ab + n_l0;
  f32x2* l10ab = l5ab + n_l5;
  float* s10b  = (float*)(l10ab + n_l10);
  float* s5b   = s10b + n_l10;
  unsigned short* s0b = (unsigned short*)(s5b + n_l5);
  unsigned short* wt  = s0b + n_l0;

  const size_t need = (n_l0 + n_l5 + n_l10) * 8 + (n_l10 + n_l5) * 4 + n_l0 * 2 + 3 * 65536 * 2;
  if (ws_size < need) {
    fill_sentinel<<<(out_size + 255) / 256, 256, 0, stream>>>(out, out_size);
    return;
  }

  prep_weights<<<96, 256, 0, stream>>>(Wz, Wh, Wo, wt);
  init_e0<<<8, 256, 0, stream>>>(l0ab);
  gemm_zh<<<Bsz * Tsz / 64, 256, 36864, stream>>>(xs, wt, bz, bh, l0ab);

  // up: L0 -> L5, L5 -> L10
  chunk_up<<<(Bsz * 512 * 256) / 256, 256, 0, stream>>>(l0ab, l5ab, 512, NL0);
  chunk_up<<<(Bsz * 16 * 256) / 256, 256, 0, stream>>>(l5ab, l10ab, 16, NL5);
  // top tree: exact scan of L10
  tree16<<<8, 256, 0, stream>>>(l10ab, s10b);
  // down: L5 scan (fp32), then L0 scan (bf16, feeds gemm_out)
  chunk_down<false><<<(Bsz * 16 * 256) / 256, 256, 0, stream>>>(l5ab, s10b, (void*)s5b, 16, 16, NL5);
  chunk_down<true><<<(Bsz * 513 * 256) / 256, 256, 0, stream>>>(l0ab, s5b, (void*)s0b, 513, 512, NL0);

  gemm_out<<<(Bsz * Tsz / 128) * 2, 256, 32768, stream>>>(s0b, wt + 2 * 65536, bo, out);
}

// Round 4
// 183.153 us; speedup vs baseline: 3.8753x; 1.7379x over previous
//
#include <hip/hip_runtime.h>

#define Bsz 8
#define Tsz 16384
#define NL0 16385
#define NL5 512
#define NL10 16

typedef __attribute__((ext_vector_type(2))) float f32x2;
typedef __attribute__((ext_vector_type(4))) float f32x4;
typedef __attribute__((ext_vector_type(8))) short bf16x8;

__device__ __forceinline__ short f2bf(float f) {
  unsigned u = __builtin_bit_cast(unsigned, f);
  u += 0x7FFFu + ((u >> 16) & 1u);
  return (short)(u >> 16);
}
__device__ __forceinline__ bf16x8 pack8(f32x4 a, f32x4 b) {
  bf16x8 v;
  v[0] = f2bf(a[0]); v[1] = f2bf(a[1]); v[2] = f2bf(a[2]); v[3] = f2bf(a[3]);
  v[4] = f2bf(b[0]); v[5] = f2bf(b[1]); v[6] = f2bf(b[2]); v[7] = f2bf(b[3]);
  return v;
}
__device__ __forceinline__ void unpk(unsigned u, float& a, float& b) {
  a = __builtin_bit_cast(float, u << 16);
  b = __builtin_bit_cast(float, u & 0xFFFF0000u);
}

// ---------------------------------------------------------------- sentinel
__global__ void fill_sentinel(float* __restrict__ out, int n) {
  int i = blockIdx.x * blockDim.x + threadIdx.x;
  if (i < n) out[i] = 12345.0f;
}

// ---------------------------------------------------------------- weight prep: fp32 [256][256] -> bf16 tiled [c/8][r][c%8]
__global__ void prep_weights(const float* __restrict__ Wz, const float* __restrict__ Wh,
                             const float* __restrict__ Wo, unsigned short* __restrict__ wt) {
  int idx = blockIdx.x * 256 + threadIdx.x;          // 3 * 256 * 32
  if (idx >= 3 * 256 * 32) return;
  int m   = idx >> 13;
  int rem = idx & 8191;
  int r   = rem >> 5;
  int cq  = rem & 31;
  const float* src = (m == 0 ? Wz : (m == 1 ? Wh : Wo)) + r * 256 + cq * 8;
  f32x4 v0 = *(const f32x4*)src;
  f32x4 v1 = *(const f32x4*)(src + 4);
  *(bf16x8*)(wt + m * 65536 + (cq * 256 + r) * 8) = pack8(v0, v1);
}

// ---------------------------------------------------------------- init element 0 of L0: (a,b) = (1,0) packed bf16
__global__ void init_e0(unsigned* __restrict__ l0) {
  int idx = blockIdx.x * 256 + threadIdx.x;
  if (idx >= Bsz * 256) return;
  int batch = idx >> 8, h = idx & 255;
  l0[(size_t)batch * NL0 * 256 + h] = 0x00003F80u;   // a=1.0 (low), b=0.0 (high)
}

// ---------------------------------------------------------------- GEMM 1: M=64 x N=256 (full H), z & h fused, L0 bf16 out
// 512 thr / 8 waves (each wave N=32). A double-buffered in LDS (linear writes);
// W fragments read directly from pre-tiled bf16 (L2-resident).
__global__ __launch_bounds__(512, 4)
void gemm_zh(const float* __restrict__ xs, const unsigned short* __restrict__ wt,
             const float* __restrict__ bz, const float* __restrict__ bh,
             unsigned* __restrict__ l0)
{
  __shared__ __align__(16) unsigned short aL[2][4096];   // 2 x (8 k-octets x 64 rows x 8)

  const int tid = threadIdx.x;
  const int wave = tid >> 6, lane = tid & 63, l15 = lane & 15, l4 = lane >> 4;
  const int rowBase = blockIdx.x * 64;
  const int srow = tid & 63, soct = tid >> 6;            // staging coords
  const float* aptr = xs + (size_t)(rowBase + srow) * 256 + soct * 8;
  const unsigned short* wz_t = wt;
  const unsigned short* wh_t = wt + 65536;

  f32x4 accz[4][2] = {};
  f32x4 acch[4][2] = {};

  f32x4 av0 = *(const f32x4*)(aptr);
  f32x4 av1 = *(const f32x4*)(aptr + 4);
  *(bf16x8*)&aL[0][(soct * 64 + srow) * 8] = pack8(av0, av1);

  const int wn = wave * 32;
  for (int S = 0; S < 4; ++S) {                          // K-stage = 64
    __syncthreads();
    const int cur = S & 1;
    if (S < 3) {
      av0 = *(const f32x4*)(aptr + (S + 1) * 64);
      av1 = *(const f32x4*)(aptr + (S + 1) * 64 + 4);
    }
#pragma unroll
    for (int k2 = 0; k2 < 2; ++k2) {                     // two K=32 MFMA slices
      bf16x8 af[4], zf[2], hf[2];
#pragma unroll
      for (int m = 0; m < 4; ++m)
        af[m] = *(const bf16x8*)&aL[cur][((k2 * 4 + l4) * 64 + m * 16 + l15) * 8];
      const int cq = (S * 2 + k2) * 4 + l4;
#pragma unroll
      for (int n = 0; n < 2; ++n) {
        const int r = wn + n * 16 + l15;
        zf[n] = *(const bf16x8*)(wz_t + (cq * 256 + r) * 8);
        hf[n] = *(const bf16x8*)(wh_t + (cq * 256 + r) * 8);
      }
#pragma unroll
      for (int m = 0; m < 4; ++m)
#pragma unroll
        for (int n = 0; n < 2; ++n) {
          accz[m][n] = __builtin_amdgcn_mfma_f32_16x16x32_bf16(af[m], zf[n], accz[m][n], 0, 0, 0);
          acch[m][n] = __builtin_amdgcn_mfma_f32_16x16x32_bf16(af[m], hf[n], acch[m][n], 0, 0, 0);
        }
    }
    if (S < 3)
      *(bf16x8*)&aL[cur ^ 1][(soct * 64 + srow) * 8] = pack8(av0, av1);
  }

  const int batch = rowBase >> 14;
  const int tRow  = rowBase & (Tsz - 1);
#pragma unroll
  for (int n = 0; n < 2; ++n) {
    const int col = wn + n * 16 + l15;
    const float bzv = bz[col], bhv = bh[col];
#pragma unroll
    for (int m = 0; m < 4; ++m)
#pragma unroll
      for (int j = 0; j < 4; ++j) {
        const int t = tRow + m * 16 + l4 * 4 + j;
        const float zv = 1.0f / (1.0f + __expf(-(accz[m][n][j] + bzv)));
        const float hv = acch[m][n][j] + bhv;
        unsigned u = (unsigned)(unsigned short)f2bf(1.0f - zv)
                   | ((unsigned)(unsigned short)f2bf(zv * hv) << 16);
        l0[((size_t)batch * NL0 + t + 1) * 256 + col] = u;
      }
  }
}

// ---------------------------------------------------------------- chunk up-sweep from bf16 L0: 32 elems -> 1 (5 levels), 2 h per thread
__global__ __launch_bounds__(256)
void chunk_up_bf16(const unsigned* __restrict__ l0, f32x2* __restrict__ dst)
{
  int idx = blockIdx.x * 256 + threadIdx.x;              // Bsz*512*128
  int h2 = idx & 127, r = idx >> 7;
  int c = r & 511, batch = r >> 9;
  size_t base = ((size_t)batch * NL0 + (size_t)c * 32) * 256 + h2 * 2;

  float ax[16], bx[16], ay[16], by[16];
#pragma unroll
  for (int i = 0; i < 16; ++i) {
    uint2 e0 = *(const uint2*)(l0 + base + (size_t)(2 * i) * 256);
    uint2 e1 = *(const uint2*)(l0 + base + (size_t)(2 * i + 1) * 256);
    float a0, b0, a1, b1;
    unpk(e0.x, a0, b0); unpk(e1.x, a1, b1);
    ax[i] = a0 * b0; bx[i] = b0 * a1 + b1;
    unpk(e0.y, a0, b0); unpk(e1.y, a1, b1);
    ay[i] = a0 * b0; by[i] = b0 * a1 + b1;
  }
#pragma unroll
  for (int n = 8; n >= 1; n >>= 1) {
#pragma unroll
    for (int i = 0; i < n; ++i) {
      float nax = ax[2*i] * bx[2*i], nbx = bx[2*i] * ax[2*i+1] + bx[2*i+1];
      float nay = ay[2*i] * by[2*i], nby = by[2*i] * ay[2*i+1] + by[2*i+1];
      ax[i] = nax; bx[i] = nbx; ay[i] = nay; by[i] = nby;
    }
  }
  f32x4 o = {ax[0], bx[0], ay[0], by[0]};
  *(f32x4*)((float*)dst + (((size_t)batch * 512 + c) * 256 + h2 * 2) * 2) = o;
}

// ---------------------------------------------------------------- chunk up-sweep f32 (L5 -> L10)
__global__ __launch_bounds__(256)
void chunk_up(const f32x2* __restrict__ src, f32x2* __restrict__ dst, int nCh, int nSrc)
{
  int idx = blockIdx.x * 256 + threadIdx.x;
  int total = Bsz * nCh * 256;
  if (idx >= total) return;
  int h = idx & 255, r = idx >> 8;
  int c = r % nCh, batch = r / nCh;
  size_t base = ((size_t)batch * nSrc + (size_t)c * 32) * 256 + h;

  float a1[16], b1[16];
#pragma unroll
  for (int i = 0; i < 16; ++i) {
    f32x2 e0 = src[base + (size_t)(2 * i) * 256];
    f32x2 e1 = src[base + (size_t)(2 * i + 1) * 256];
    a1[i] = e0[0] * e0[1];
    b1[i] = e0[1] * e1[0] + e1[1];
  }
#pragma unroll
  for (int n = 8; n >= 1; n >>= 1) {
#pragma unroll
    for (int i = 0; i < n; ++i) {
      float na = a1[2 * i] * b1[2 * i];
      float nb = b1[2 * i] * a1[2 * i + 1] + b1[2 * i + 1];
      a1[i] = na; b1[i] = nb;
    }
  }
  dst[((size_t)batch * nCh + c) * 256 + h] = f32x2{a1[0], b1[0]};
}

// ---------------------------------------------------------------- 16-element full tree scan (top levels), exact b-scan
__global__ void tree16(const f32x2* __restrict__ src, float* __restrict__ outB)
{
  int idx = blockIdx.x * 256 + threadIdx.x;
  if (idx >= Bsz * 256) return;
  int h = idx & 255, batch = idx >> 8;
  size_t base = (size_t)batch * 16 * 256 + h;

  float a0[16], b0[16];
#pragma unroll
  for (int i = 0; i < 16; ++i) { f32x2 e = src[base + (size_t)i * 256]; a0[i] = e[0]; b0[i] = e[1]; }
  float a1[8], b1[8];
#pragma unroll
  for (int i = 0; i < 8; ++i) { a1[i] = a0[2*i]*b0[2*i]; b1[i] = b0[2*i]*a0[2*i+1] + b0[2*i+1]; }
  float a2[4], b2[4];
#pragma unroll
  for (int i = 0; i < 4; ++i) { a2[i] = a1[2*i]*b1[2*i]; b2[i] = b1[2*i]*a1[2*i+1] + b1[2*i+1]; }
  float a3[2], b3[2];
#pragma unroll
  for (int i = 0; i < 2; ++i) { a3[i] = a2[2*i]*b2[2*i]; b3[i] = b2[2*i]*a2[2*i+1] + b2[2*i+1]; }
  float s3[2];
  s3[0] = b3[0];
  s3[1] = b3[0] * a3[1] + b3[1];
  float s2[4];
  s2[0] = b2[0]; s2[1] = s3[0]; s2[2] = s3[0] * a2[2] + b2[2]; s2[3] = s3[1];
  float s1[8];
  s1[0] = b1[0];
#pragma unroll
  for (int j = 0; j < 4; ++j) s1[2*j+1] = s2[j];
#pragma unroll
  for (int j = 1; j < 4; ++j) s1[2*j] = s2[j-1] * a1[2*j] + b1[2*j];
  float s0[16];
  s0[0] = b0[0];
#pragma unroll
  for (int j = 0; j < 8; ++j) s0[2*j+1] = s1[j];
#pragma unroll
  for (int j = 1; j < 8; ++j) s0[2*j] = s1[j-1] * a0[2*j] + b0[2*j];
#pragma unroll
  for (int i = 0; i < 16; ++i) outB[base + (size_t)i * 256] = s0[i];
}

// ---------------------------------------------------------------- chunk down-sweep f32 (L5 level): needs P=snext[c-1], S=snext[c]
__global__ __launch_bounds__(256, 2)
void chunk_down_f32(const f32x2* __restrict__ src, const float* __restrict__ snext,
                    float* __restrict__ outF, int nCh, int nFull, int nSrc)
{
  int idx = blockIdx.x * 256 + threadIdx.x;
  int total = Bsz * nCh * 256;
  if (idx >= total) return;
  int h = idx & 255, r = idx >> 8;
  int c = r % nCh, batch = r / nCh;
  size_t base = ((size_t)batch * nSrc + (size_t)c * 32) * 256 + h;
  bool hasP = (c > 0);
  float P = hasP ? snext[((size_t)batch * nFull + (c - 1)) * 256 + h] : 0.0f;
  float S = snext[((size_t)batch * nFull + c) * 256 + h];

  float ae[16], be[16], a1[16], b1[16];
#pragma unroll
  for (int i = 0; i < 16; ++i) {
    f32x2 e0 = src[base + (size_t)(2 * i) * 256];
    f32x2 e1 = src[base + (size_t)(2 * i + 1) * 256];
    ae[i] = e0[0]; be[i] = e0[1];
    a1[i] = e0[0] * e0[1];
    b1[i] = e0[1] * e1[0] + e1[1];
  }
  float a2[8], b2[8];
#pragma unroll
  for (int i = 0; i < 8; ++i) { a2[i] = a1[2*i]*b1[2*i]; b2[i] = b1[2*i]*a1[2*i+1] + b1[2*i+1]; }
  float a3[4], b3[4];
#pragma unroll
  for (int i = 0; i < 4; ++i) { a3[i] = a2[2*i]*b2[2*i]; b3[i] = b2[2*i]*a2[2*i+1] + b2[2*i+1]; }
  float a4[2], b4[2];
#pragma unroll
  for (int i = 0; i < 2; ++i) { a4[i] = a3[2*i]*b3[2*i]; b4[i] = b3[2*i]*a3[2*i+1] + b3[2*i+1]; }

  float s4[2];
  s4[0] = hasP ? P * a4[0] + b4[0] : b4[0];
  s4[1] = S;
  float s3[4];
  s3[0] = hasP ? P * a3[0] + b3[0] : b3[0];
  s3[1] = s4[0]; s3[2] = s4[0] * a3[2] + b3[2]; s3[3] = s4[1];
  float s2[8];
  s2[0] = hasP ? P * a2[0] + b2[0] : b2[0];
#pragma unroll
  for (int j = 0; j < 4; ++j) s2[2*j+1] = s3[j];
#pragma unroll
  for (int j = 1; j < 4; ++j) s2[2*j] = s3[j-1] * a2[2*j] + b2[2*j];
  float s1[16];
  s1[0] = hasP ? P * a1[0] + b1[0] : b1[0];
#pragma unroll
  for (int j = 0; j < 8; ++j) s1[2*j+1] = s2[j];
#pragma unroll
  for (int j = 1; j < 8; ++j) s1[2*j] = s2[j-1] * a1[2*j] + b1[2*j];

  outF[base] = hasP ? P * ae[0] + be[0] : be[0];
#pragma unroll
  for (int j = 0; j < 16; ++j) outF[base + (size_t)(2*j+1) * 256] = s1[j];
#pragma unroll
  for (int j = 1; j < 16; ++j) outF[base + (size_t)(2*j) * 256] = s1[j-1] * ae[j] + be[j];
}

// ---------------------------------------------------------------- fused L0 down-sweep + output projection
// block = (batch, chunk c of 32 L0 elems). Scan in regs -> swizzled LDS bf16 -> 32x256x256 MFMA.
__global__ __launch_bounds__(256, 2)
void down_proj(const unsigned* __restrict__ l0, const float* __restrict__ s5b,
               const unsigned short* __restrict__ wo_t, const float* __restrict__ bo,
               float* __restrict__ out)
{
  __shared__ unsigned short pL[32 * 256];   // [row][h], h XOR-swizzled by ((row&7)<<3)

  const int tid = threadIdx.x;
  const int bc = blockIdx.x;
  const int c = bc % 513;
  const int batch = bc / 513;

  {  // ---- scan phase: thread = h
    const int h = tid;
    const size_t base = ((size_t)batch * NL0 + (size_t)c * 32) * 256 + h;
    const bool hasP = (c > 0);
    const float P = hasP ? s5b[((size_t)batch * 512 + (c - 1)) * 256 + h] : 0.0f;

    if (c == 512) {                          // single tail element (t = 16383)
      float a0, b0; unpk(l0[base], a0, b0);
      pL[h] = (unsigned short)f2bf(P * a0 + b0);
#pragma unroll
      for (int i = 1; i < 32; ++i)
        pL[i * 256 + (h ^ ((i & 7) << 3))] = 0;
    } else {
      const float S = s5b[((size_t)batch * 512 + c) * 256 + h];
      float ae[16], be[16], a1[16], b1[16];
#pragma unroll
      for (int i = 0; i < 16; ++i) {
        unsigned u0 = l0[base + (size_t)(2 * i) * 256];
        unsigned u1 = l0[base + (size_t)(2 * i + 1) * 256];
        float a0, b0, a1e, b1e;
        unpk(u0, a0, b0); unpk(u1, a1e, b1e);
        ae[i] = a0; be[i] = b0;
        a1[i] = a0 * b0; b1[i] = b0 * a1e + b1e;
      }
      float a2[8], b2[8];
#pragma unroll
      for (int i = 0; i < 8; ++i) { a2[i] = a1[2*i]*b1[2*i]; b2[i] = b1[2*i]*a1[2*i+1] + b1[2*i+1]; }
      float a3[4], b3[4];
#pragma unroll
      for (int i = 0; i < 4; ++i) { a3[i] = a2[2*i]*b2[2*i]; b3[i] = b2[2*i]*a2[2*i+1] + b2[2*i+1]; }
      float a4[2], b4[2];
#pragma unroll
      for (int i = 0; i < 2; ++i) { a4[i] = a3[2*i]*b3[2*i]; b4[i] = b3[2*i]*a3[2*i+1] + b3[2*i+1]; }

      float s4[2];
      s4[0] = hasP ? P * a4[0] + b4[0] : b4[0];
      s4[1] = S;
      float s3[4];
      s3[0] = hasP ? P * a3[0] + b3[0] : b3[0];
      s3[1] = s4[0]; s3[2] = s4[0] * a3[2] + b3[2]; s3[3] = s4[1];
      float s2[8];
      s2[0] = hasP ? P * a2[0] + b2[0] : b2[0];
#pragma unroll
      for (int j = 0; j < 4; ++j) s2[2*j+1] = s3[j];
#pragma unroll
      for (int j = 1; j < 4; ++j) s2[2*j] = s3[j-1] * a2[2*j] + b2[2*j];
      float s1[16];
      s1[0] = hasP ? P * a1[0] + b1[0] : b1[0];
#pragma unroll
      for (int j = 0; j < 8; ++j) s1[2*j+1] = s2[j];
#pragma unroll
      for (int j = 1; j < 8; ++j) s1[2*j] = s2[j-1] * a1[2*j] + b1[2*j];

      pL[h] = (unsigned short)f2bf(hasP ? P * ae[0] + be[0] : be[0]);
#pragma unroll
      for (int j = 0; j < 16; ++j) {
        const int row = 2 * j + 1;
        pL[row * 256 + (h ^ ((row & 7) << 3))] = (unsigned short)f2bf(s1[j]);
      }
#pragma unroll
      for (int j = 1; j < 16; ++j) {
        const int row = 2 * j;
        pL[row * 256 + (h ^ ((row & 7) << 3))] = (unsigned short)f2bf(s1[j-1] * ae[j] + be[j]);
      }
    }
  }
  __syncthreads();

  // ---- projection phase: M=32, N=64/wave, K=256; Wo frags from L2
  const int wave = tid >> 6, lane = tid & 63, l15 = lane & 15, l4 = lane >> 4;
  const int wn = wave * 64;
  f32x4 acc[2][4] = {};
#pragma unroll
  for (int kk = 0; kk < 8; ++kk) {
    bf16x8 af[2], wf[4];
#pragma unroll
    for (int m = 0; m < 2; ++m) {
      const int row = m * 16 + l15;
      af[m] = *(const bf16x8*)&pL[row * 256 + ((kk * 32 + l4 * 8) ^ ((row & 7) << 3))];
    }
#pragma unroll
    for (int n = 0; n < 4; ++n)
      wf[n] = *(const bf16x8*)(wo_t + ((kk * 4 + l4) * 256 + wn + n * 16 + l15) * 8);
#pragma unroll
    for (int m = 0; m < 2; ++m)
#pragma unroll
      for (int n = 0; n < 4; ++n)
        acc[m][n] = __builtin_amdgcn_mfma_f32_16x16x32_bf16(af[m], wf[n], acc[m][n], 0, 0, 0);
  }

  const int tBase = 32 * c - 1;
#pragma unroll
  for (int n = 0; n < 4; ++n) {
    const int col = wn + n * 16 + l15;
    const float bv = bo[col];
#pragma unroll
    for (int m = 0; m < 2; ++m)
#pragma unroll
      for (int j = 0; j < 4; ++j) {
        const int t = tBase + m * 16 + l4 * 4 + j;
        if ((unsigned)t < (unsigned)Tsz)
          out[((size_t)batch * Tsz + t) * 256 + col] = acc[m][n][j] + bv;
      }
  }
}

// ================================================================ host
extern "C" void kernel_launch(void* const* d_in, const int* in_sizes, int n_in,
                              void* d_out, int out_size, void* d_ws, size_t ws_size,
                              hipStream_t stream)
{
  (void)in_sizes; (void)n_in;
  const float* xs = (const float*)d_in[0];
  const float* Wz = (const float*)d_in[1];
  const float* bz = (const float*)d_in[2];
  const float* Wh = (const float*)d_in[3];
  const float* bh = (const float*)d_in[4];
  const float* Wo = (const float*)d_in[5];
  const float* bo = (const float*)d_in[6];
  float* out = (float*)d_out;

  const size_t n_l0  = (size_t)Bsz * NL0 * 256;
  const size_t n_l5  = (size_t)Bsz * NL5 * 256;
  const size_t n_l10 = (size_t)Bsz * NL10 * 256;

  unsigned* l0    = (unsigned*)d_ws;
  f32x2* l5ab     = (f32x2*)(l0 + n_l0);
  f32x2* l10ab    = l5ab + n_l5;
  float* s10b     = (float*)(l10ab + n_l10);
  float* s5b      = s10b + n_l10;
  unsigned short* wt = (unsigned short*)(s5b + n_l5);

  const size_t need = n_l0 * 4 + n_l5 * 8 + n_l10 * 8 + n_l10 * 4 + n_l5 * 4 + 3 * 65536 * 2;
  if (ws_size < need) {
    fill_sentinel<<<(out_size + 255) / 256, 256, 0, stream>>>(out, out_size);
    return;
  }

  prep_weights<<<96, 256, 0, stream>>>(Wz, Wh, Wo, wt);
  init_e0<<<8, 256, 0, stream>>>(l0);
  gemm_zh<<<Bsz * Tsz / 64, 512, 0, stream>>>(xs, wt, bz, bh, l0);

  chunk_up_bf16<<<(Bsz * 512 * 128) / 256, 256, 0, stream>>>(l0, l5ab);
  chunk_up<<<(Bsz * 16 * 256) / 256, 256, 0, stream>>>(l5ab, l10ab, 16, NL5);
  tree16<<<8, 256, 0, stream>>>(l10ab, s10b);
  chunk_down_f32<<<(Bsz * 16 * 256) / 256, 256, 0, stream>>>(l5ab, s10b, s5b, 16, 16, NL5);

  down_proj<<<Bsz * 513, 256, 0, stream>>>(l0, s5b, wt + 2 * 65536, bo, out);
}